// Round 1
// baseline (363.651 us; speedup 1.0000x reference)
//
#include <hip/hip_runtime.h>

#define GLOVE_BATCH 262144
#define EMB 300
#define VEC4 (EMB / 4)   // 75 float4 per row

__global__ void glove_zero_out(float* out) {
    if (threadIdx.x == 0 && blockIdx.x == 0) out[0] = 0.0f;
}

__global__ __launch_bounds__(256) void glove_loss_kernel(
    const int*   __restrict__ center,
    const int*   __restrict__ outside,
    const float* __restrict__ coocs,
    const float* __restrict__ weighting,
    const float* __restrict__ cemb,
    const float* __restrict__ oemb,
    const float* __restrict__ cbias,
    const float* __restrict__ obias,
    float*       __restrict__ out)
{
    const int lane    = threadIdx.x & 63;
    const int warp    = threadIdx.x >> 6;
    const int wave_id = blockIdx.x * 4 + warp;
    const int n_waves = gridDim.x * 4;

    float local = 0.0f;

    for (int p = wave_id; p < GLOVE_BATCH; p += n_waves) {
        const int ci = center[p];
        const int oi = outside[p];
        const float4* __restrict__ ca = (const float4*)(cemb + (long)ci * EMB);
        const float4* __restrict__ ob = (const float4*)(oemb + (long)oi * EMB);

        float acc = 0.0f;
        // 75 float4 per row: lanes 0..63 cover [0,64), lanes 0..10 cover [64,75)
        {
            float4 a = ca[lane];
            float4 b = ob[lane];
            acc += a.x * b.x + a.y * b.y + a.z * b.z + a.w * b.w;
        }
        if (lane < VEC4 - 64) {
            float4 a = ca[lane + 64];
            float4 b = ob[lane + 64];
            acc += a.x * b.x + a.y * b.y + a.z * b.z + a.w * b.w;
        }

        // wave-wide reduction (64 lanes)
        #pragma unroll
        for (int off = 32; off > 0; off >>= 1)
            acc += __shfl_down(acc, off, 64);

        if (lane == 0) {
            const float err = acc + cbias[ci] + obias[oi] - coocs[p];
            local += weighting[p] * err * err;
        }
    }

    __shared__ float smem[4];
    if (lane == 0) smem[warp] = local;
    __syncthreads();
    if (threadIdx.x == 0) {
        const float s = smem[0] + smem[1] + smem[2] + smem[3];
        atomicAdd(out, s);
    }
}

extern "C" void kernel_launch(void* const* d_in, const int* in_sizes, int n_in,
                              void* d_out, int out_size, void* d_ws, size_t ws_size,
                              hipStream_t stream) {
    const int*   center    = (const int*)  d_in[0];
    const int*   outside   = (const int*)  d_in[1];
    const float* coocs     = (const float*)d_in[2];
    const float* weighting = (const float*)d_in[3];
    const float* cemb      = (const float*)d_in[4];
    const float* oemb      = (const float*)d_in[5];
    const float* cbias     = (const float*)d_in[6];
    const float* obias     = (const float*)d_in[7];
    float* out = (float*)d_out;

    glove_zero_out<<<1, 64, 0, stream>>>(out);

    // 8192 blocks x 4 waves = 32768 waves, 8 pairs per wave
    glove_loss_kernel<<<8192, 256, 0, stream>>>(
        center, outside, coocs, weighting, cemb, oemb, cbias, obias, out);
}

// Round 2
// 309.155 us; speedup vs baseline: 1.1763x; 1.1763x over previous
//
#include <hip/hip_runtime.h>

#define BATCH 262144
#define EMB 300
#define NBLK 4096
#define WPB 4                    // waves per block
#define PAIRS_PER_WAVE 16        // BATCH / (NBLK * WPB)
#define UNROLL 4

__global__ __launch_bounds__(256) void glove_main(
    const int*   __restrict__ center,
    const int*   __restrict__ outside,
    const float* __restrict__ coocs,
    const float* __restrict__ weighting,
    const float* __restrict__ cemb,
    const float* __restrict__ oemb,
    const float* __restrict__ cbias,
    const float* __restrict__ obias,
    float*       __restrict__ block_sums)
{
    const int lane = threadIdx.x & 63;
    const int warp = threadIdx.x >> 6;
    const int wave_base = (blockIdx.x * WPB + warp) * PAIRS_PER_WAVE;

    float local = 0.0f;

    #pragma unroll
    for (int it = 0; it < PAIRS_PER_WAVE / UNROLL; ++it) {
        const int p0 = wave_base + it * UNROLL;

        int   ci[UNROLL], oi[UNROLL];
        float cb[UNROLL], ob2[UNROLL], cc[UNROLL], wt[UNROLL];
        float acc[UNROLL];

        #pragma unroll
        for (int j = 0; j < UNROLL; ++j) {
            ci[j] = center[p0 + j];
            oi[j] = outside[p0 + j];
        }
        // wave-uniform broadcast loads — issue early, overlap with row loads
        #pragma unroll
        for (int j = 0; j < UNROLL; ++j) {
            cc[j]  = coocs[p0 + j];
            wt[j]  = weighting[p0 + j];
            cb[j]  = cbias[ci[j]];
            ob2[j] = obias[oi[j]];
        }
        // row gathers: 8 full dwordx4 + 8 masked dwordx4 in flight
        #pragma unroll
        for (int j = 0; j < UNROLL; ++j) {
            const float4* __restrict__ A = (const float4*)(cemb + (long)ci[j] * EMB);
            const float4* __restrict__ B = (const float4*)(oemb + (long)oi[j] * EMB);
            float4 a = A[lane];
            float4 b = B[lane];
            float s = a.x * b.x + a.y * b.y + a.z * b.z + a.w * b.w;
            if (lane < 11) {  // 75 float4 per row: lanes 0..10 cover [64,75)
                float4 a2 = A[lane + 64];
                float4 b2 = B[lane + 64];
                s += a2.x * b2.x + a2.y * b2.y + a2.z * b2.z + a2.w * b2.w;
            }
            acc[j] = s;
        }
        // 4 interleaved shuffle-reduction chains: 6 waits total, not 24
        #pragma unroll
        for (int off = 32; off > 0; off >>= 1) {
            #pragma unroll
            for (int j = 0; j < UNROLL; ++j)
                acc[j] += __shfl_down(acc[j], off, 64);
        }
        if (lane == 0) {
            #pragma unroll
            for (int j = 0; j < UNROLL; ++j) {
                const float e = acc[j] + cb[j] + ob2[j] - cc[j];
                local += wt[j] * e * e;
            }
        }
    }

    __shared__ float smem[WPB];
    if (lane == 0) smem[warp] = local;
    __syncthreads();
    if (threadIdx.x == 0)
        block_sums[blockIdx.x] = smem[0] + smem[1] + smem[2] + smem[3];
}

__global__ __launch_bounds__(1024) void glove_reduce(
    const float* __restrict__ part, float* __restrict__ out)
{
    const int t = threadIdx.x;
    float4 v = ((const float4*)part)[t];          // 1024 x 4 = 4096 partials
    float s = v.x + v.y + v.z + v.w;
    #pragma unroll
    for (int off = 32; off > 0; off >>= 1)
        s += __shfl_down(s, off, 64);
    __shared__ float sm[16];
    if ((t & 63) == 0) sm[t >> 6] = s;
    __syncthreads();
    if (t < 16) {
        float x = sm[t];
        #pragma unroll
        for (int off = 8; off > 0; off >>= 1)
            x += __shfl_down(x, off, 16);
        if (t == 0) out[0] = x;
    }
}

extern "C" void kernel_launch(void* const* d_in, const int* in_sizes, int n_in,
                              void* d_out, int out_size, void* d_ws, size_t ws_size,
                              hipStream_t stream) {
    const int*   center    = (const int*)  d_in[0];
    const int*   outside   = (const int*)  d_in[1];
    const float* coocs     = (const float*)d_in[2];
    const float* weighting = (const float*)d_in[3];
    const float* cemb      = (const float*)d_in[4];
    const float* oemb      = (const float*)d_in[5];
    const float* cbias     = (const float*)d_in[6];
    const float* obias     = (const float*)d_in[7];
    float* out        = (float*)d_out;
    float* block_sums = (float*)d_ws;   // NBLK floats = 16 KB, fully overwritten

    glove_main<<<NBLK, 256, 0, stream>>>(
        center, outside, coocs, weighting, cemb, oemb, cbias, obias, block_sums);
    glove_reduce<<<1, 1024, 0, stream>>>(block_sums, out);
}